// Round 2
// 162.774 us; speedup vs baseline: 1.0889x; 1.0889x over previous
//
#include <hip/hip_runtime.h>

// Problem constants (from reference)
#define B 64
#define H 128
#define W 128
#define R 4
#define GW 32
#define N 1024
#define D 16
#define S 32
// One block per n, 128 threads, each thread owns 4 consecutive (d,s) elements.
// Pesos is read EXACTLY once per line (b-splitting re-reads pesos at a net loss).
//
// R3/R4 change (resubmitted after container failure): drop ALL nontemporal
// access. The harness fill kernel reaches 6.45 TB/s with normal cached stores
// (full dirty lines via L2 write-back); nt stores bypass L2 and may take a
// slower uncached-write path. nt loads bypass L1, so the 4x 16-B reads per
// 64-B pesos line (diag offsets 0/5/10/15) re-fetch each line 4x. Cached
// loads make 3 of the 4 L1 hits.
// Also: pesos loads are issued BEFORE the x-staging + barrier (they do not
// depend on LDS), overlapping their latency with the staging phase.

typedef float vf4 __attribute__((ext_vector_type(4)));

__global__ __launch_bounds__(128) void conexao_regional_kernel(
    const float* __restrict__ x,       // [B,1,H,W]
    const float* __restrict__ pesos,   // [N,D,S,R,R]
    float* __restrict__ out)           // [B,N,D,S]
{
    __shared__ float sx[B][R];  // patch diagonals for this block's n (1 KB)

    const int n   = blockIdx.x;
    const int tid = threadIdx.x;

    // --- issue weight loads first (independent of the LDS staging) ---
    // pesos[n,d,s,:,:] is a contiguous 16-float (64 B) block at (n*512+e)*16;
    // diagonal elements sit at offsets 0, 5, 10, 15 within it.
    const int  e0    = tid * 4;                         // element in [0,512)
    const long pbase = ((long)n * 512 + e0) * 16;       // in floats
    vf4 q[4][4];
#pragma unroll
    for (int k = 0; k < 4; ++k) {
        const vf4* p = (const vf4*)(pesos + pbase + (long)k * 16);
        q[k][0] = p[0];
        q[k][1] = p[1];
        q[k][2] = p[2];
        q[k][3] = p[3];
    }

    // --- stage xd[b][r] = x[b, 0, i*R+r, j*R+r] into LDS ---
    // flat addr: b*H*W + (i*R)*W + j*R + r*(W+1)
    const int i = n / GW, j = n % GW;
    const int xbase = i * (R * W) + j * R;
    for (int t = tid; t < B * R; t += 128) {
        const int b = t >> 2, r = t & 3;
        sx[b][r] = x[b * (H * W) + xbase + r * (W + 1)];
    }
    __syncthreads();

    // --- extract weight diagonals ---
    float w[4][4];
#pragma unroll
    for (int k = 0; k < 4; ++k) {
        w[k][0] = q[k][0].x;  // [r=0][r=0] -> offset 0
        w[k][1] = q[k][1].y;  // [1][1]     -> offset 5
        w[k][2] = q[k][2].z;  // [2][2]     -> offset 10
        w[k][3] = q[k][3].w;  // [3][3]     -> offset 15
    }

    // --- stream the output: 64 float4 cached stores ---
    float* outp = out + (long)n * 512 + e0;
#pragma unroll 8
    for (int b = 0; b < B; ++b) {
        const vf4 xv = *(const vf4*)&sx[b][0];   // one ds_read_b128 (broadcast)
        vf4 v;
        v.x = w[0][0] * xv.x + w[0][1] * xv.y + w[0][2] * xv.z + w[0][3] * xv.w;
        v.y = w[1][0] * xv.x + w[1][1] * xv.y + w[1][2] * xv.z + w[1][3] * xv.w;
        v.z = w[2][0] * xv.x + w[2][1] * xv.y + w[2][2] * xv.z + w[2][3] * xv.w;
        v.w = w[3][0] * xv.x + w[3][1] * xv.y + w[3][2] * xv.z + w[3][3] * xv.w;
        *(vf4*)(outp + (long)b * (N * D * S)) = v;
    }
}

extern "C" void kernel_launch(void* const* d_in, const int* in_sizes, int n_in,
                              void* d_out, int out_size, void* d_ws, size_t ws_size,
                              hipStream_t stream) {
    const float* x     = (const float*)d_in[0];   // [64,1,128,128]
    const float* pesos = (const float*)d_in[1];   // [1024,16,32,4,4]
    float* out = (float*)d_out;                    // [64,1024,16,32]

    conexao_regional_kernel<<<N, 128, 0, stream>>>(x, pesos, out);
}